// Round 5
// baseline (15.376 us; speedup 1.0000x reference)
//
#include <hip/hip_runtime.h>

#define B_SZ  64
#define L_SZ  4096
#define VOCAB 33
#define D_SZ  256

// ws layout (float offsets)
#define EW1_OFF 0                      // [33][256] f32 = emb @ W1
#define CNT_OFF (VOCAB * D_SZ)         // [64][33]  f32 histogram counts

// ---------------- Kernel A ----------------
// blocks 0..131  : EW1 = emb @ W1.  bid -> (v = bid%33, cg = bid/33)
//                  each block: 64-column slice of EW1 row v, k-split 4.
// blocks 132..195: histogram of row hb = bid-132 over valid prefix.
__global__ __launch_bounds__(256) void prot_prep(
    const int* __restrict__ X,
    const int* __restrict__ valid_lens,
    const float* __restrict__ emb,
    const float* __restrict__ W1,
    float* __restrict__ ws)
{
    const int bid = blockIdx.x;
    const int t   = threadIdx.x;

    if (bid < 132) {
        __shared__ float s_e[D_SZ];
        __shared__ float s_red[4][64];
        const int v  = bid % 33;
        const int cg = bid / 33;           // 0..3
        s_e[t] = emb[v * D_SZ + t];
        __syncthreads();
        const int kk = t >> 6;             // 0..3
        const int c  = t & 63;
        float acc = 0.f;
        #pragma unroll
        for (int j = 0; j < 64; ++j) {
            const int k = kk * 64 + j;
            acc = fmaf(s_e[k], W1[k * D_SZ + cg * 64 + c], acc);
        }
        s_red[kk][c] = acc;
        __syncthreads();
        if (t < 64) {
            float e = s_red[0][t] + s_red[1][t] + s_red[2][t] + s_red[3][t];
            ws[EW1_OFF + v * D_SZ + cg * 64 + t] = e;
        }
    } else {
        __shared__ int s_c[4][VOCAB];
        const int hb = bid - 132;
        const int wv = t >> 6;             // wave 0..3
        if (t < 4 * VOCAB) ((int*)s_c)[t] = 0;
        __syncthreads();
        const int   vl = valid_lens[hb];
        const int4* x4 = reinterpret_cast<const int4*>(X + (size_t)hb * L_SZ);
        #pragma unroll
        for (int r = 0; r < 4; ++r) {
            const int  i  = t + r * 256;
            const int4 tk = x4[i];
            const int  l0 = i * 4;
            if (l0 + 0 < vl) atomicAdd(&s_c[wv][tk.x], 1);
            if (l0 + 1 < vl) atomicAdd(&s_c[wv][tk.y], 1);
            if (l0 + 2 < vl) atomicAdd(&s_c[wv][tk.z], 1);
            if (l0 + 3 < vl) atomicAdd(&s_c[wv][tk.w], 1);
        }
        __syncthreads();
        if (t < VOCAB) {
            const int c = s_c[0][t] + s_c[1][t] + s_c[2][t] + s_c[3][t];
            ws[CNT_OFF + hb * VOCAB + t] = (float)c;
        }
    }
}

// ---------------- Kernel B ----------------
// grid 256 = (b = bid>>2, cg = bid&3); 512 threads.
// h[0..255] = relu(b1 + sum_v cnt[v]*EW1[v,:])  (33-FMA dots, EW1 is 33 KB)
// out[b, cg*64 .. +64) = relu(b2 + h @ W2[:, slice])  (8-way k-split)
__global__ __launch_bounds__(512) void prot_main(
    const float* __restrict__ ws,
    const float* __restrict__ b1,
    const float* __restrict__ W2,
    const float* __restrict__ b2,
    float* __restrict__ out)
{
    __shared__ float s_cnt[VOCAB];
    __shared__ float s_h[D_SZ];
    __shared__ float s_p[8][64];

    const int bid = blockIdx.x;
    const int t   = threadIdx.x;
    const int b   = bid >> 2;
    const int cg  = bid & 3;
    const int C0  = cg * 64;

    if (t < VOCAB) s_cnt[t] = ws[CNT_OFF + b * VOCAB + t];
    __syncthreads();

    // ---- layer 1 via EW1: 33-length dot per hidden feature ----
    if (t < D_SZ) {
        float a = b1[t];
        #pragma unroll
        for (int v = 0; v < VOCAB; ++v)
            a = fmaf(s_cnt[v], ws[EW1_OFF + v * D_SZ + t], a);
        s_h[t] = fmaxf(a, 0.f);
    }
    __syncthreads();

    // ---- layer 2, 64-column slice, k-split 8 ----
    const int kk = t >> 6;          // 0..7
    const int c  = t & 63;
    float acc = 0.f;
    #pragma unroll
    for (int j = 0; j < 32; ++j) {
        const int k = kk * 32 + j;
        acc = fmaf(s_h[k], W2[k * D_SZ + C0 + c], acc);
    }
    s_p[kk][c] = acc;
    __syncthreads();

    if (t < 64) {
        float o = b2[C0 + t];
        #pragma unroll
        for (int q = 0; q < 8; ++q) o += s_p[q][t];
        out[(size_t)b * D_SZ + C0 + t] = fmaxf(o, 0.f);
    }
}

extern "C" void kernel_launch(void* const* d_in, const int* in_sizes, int n_in,
                              void* d_out, int out_size, void* d_ws, size_t ws_size,
                              hipStream_t stream) {
    const int*   X          = (const int*)d_in[0];
    const int*   valid_lens = (const int*)d_in[1];
    const float* emb        = (const float*)d_in[2];
    const float* W1         = (const float*)d_in[3];
    const float* b1         = (const float*)d_in[4];
    const float* W2         = (const float*)d_in[5];
    const float* b2         = (const float*)d_in[6];
    float* out = (float*)d_out;
    float* ws  = (float*)d_ws;

    prot_prep<<<196, 256, 0, stream>>>(X, valid_lens, emb, W1, ws);
    prot_main<<<256, 512, 0, stream>>>(ws, b1, W2, b2, out);
}

// Round 6
// 12.705 us; speedup vs baseline: 1.2102x; 1.2102x over previous
//
#include <hip/hip_runtime.h>

#define B_SZ  64
#define L_SZ  4096
#define VOCAB 33
#define D_SZ  256

// ws layout (float offsets)
#define EW1_OFF 0                      // [33][256] f32 = emb @ W1
#define CNT_OFF (VOCAB * D_SZ)         // [64][33]  f32 histogram counts

// ---------------- Kernel A (light, wide) ----------------
// 80 blocks x 512 threads.
//  bid 0..15 : EW1[:, bid*16 .. bid*16+16) = emb @ W1[:, slice], 32-way k-split
//  bid 16..79: histogram of row (bid-16) over valid prefix
__global__ __launch_bounds__(512) void prot_prep(
    const int* __restrict__ X,
    const int* __restrict__ valid_lens,
    const float* __restrict__ emb,
    const float* __restrict__ W1,
    float* __restrict__ ws)
{
    __shared__ float s_emb[VOCAB][D_SZ];     // 33 KB
    __shared__ float s_red[32][VOCAB][16];   // 67.6 KB
    __shared__ int   s_c[8][VOCAB];

    const int bid = blockIdx.x;
    const int t   = threadIdx.x;

    if (bid < 16) {
        // ---- EW1 column-slice: reads emb (33 KB) + W1 slice (16 KB) ----
        for (int i = t; i < VOCAB * D_SZ; i += 512)
            ((float*)s_emb)[i] = emb[i];
        __syncthreads();

        const int c0 = bid * 16;
        const int c  = t & 15;
        const int kk = t >> 4;               // 0..31, k-chunk of 8
        float acc[VOCAB];
        #pragma unroll
        for (int v = 0; v < VOCAB; ++v) acc[v] = 0.f;
        #pragma unroll
        for (int j = 0; j < 8; ++j) {
            const int   k = kk * 8 + j;
            const float w = W1[k * D_SZ + c0 + c];
            #pragma unroll
            for (int v = 0; v < VOCAB; ++v)
                acc[v] = fmaf(s_emb[v][k], w, acc[v]);
        }
        #pragma unroll
        for (int v = 0; v < VOCAB; ++v) s_red[kk][v][c] = acc[v];
        __syncthreads();

        for (int i = t; i < VOCAB * 16; i += 512) {
            const int v  = i >> 4;
            const int cc = i & 15;
            float s = 0.f;
            #pragma unroll
            for (int k2 = 0; k2 < 32; ++k2) s += s_red[k2][v][cc];
            ws[EW1_OFF + v * D_SZ + c0 + cc] = s;
        }
    } else {
        // ---- histogram (r4's proven pattern) ----
        const int hb = bid - 16;
        const int wv = t >> 6;               // wave 0..7
        if (t < 8 * VOCAB) ((int*)s_c)[t] = 0;
        __syncthreads();
        const int   vl = valid_lens[hb];
        const int4* x4 = reinterpret_cast<const int4*>(X + (size_t)hb * L_SZ);
        const int4  t0 = x4[t];
        const int4  t1 = x4[t + 512];
        const int   l0 = t * 4;
        const int   l1 = (t + 512) * 4;
        if (l0 + 0 < vl) atomicAdd(&s_c[wv][t0.x], 1);
        if (l0 + 1 < vl) atomicAdd(&s_c[wv][t0.y], 1);
        if (l0 + 2 < vl) atomicAdd(&s_c[wv][t0.z], 1);
        if (l0 + 3 < vl) atomicAdd(&s_c[wv][t0.w], 1);
        if (l1 + 0 < vl) atomicAdd(&s_c[wv][t1.x], 1);
        if (l1 + 1 < vl) atomicAdd(&s_c[wv][t1.y], 1);
        if (l1 + 2 < vl) atomicAdd(&s_c[wv][t1.z], 1);
        if (l1 + 3 < vl) atomicAdd(&s_c[wv][t1.w], 1);
        __syncthreads();
        if (t < VOCAB) {
            int c = 0;
            #pragma unroll
            for (int w = 0; w < 8; ++w) c += s_c[w][t];
            ws[CNT_OFF + hb * VOCAB + t] = (float)c;
        }
    }
}

// ---------------- Kernel B ----------------
// 256 blocks = (b = bid>>2, cg = bid&3) x 512 threads.
// W2 slice prefetched to regs at entry (stream hides under h-phase).
// h = relu(b1 + cnt @ EW1); out slice = relu(b2 + h @ W2[:, slice]).
__global__ __launch_bounds__(512) void prot_main(
    const float* __restrict__ ws,
    const float* __restrict__ b1,
    const float* __restrict__ W2,
    const float* __restrict__ b2,
    float* __restrict__ out)
{
    __shared__ float s_cnt[VOCAB];
    __shared__ float s_h[D_SZ];
    __shared__ float s_p[8][64];

    const int bid = blockIdx.x;
    const int t   = threadIdx.x;
    const int b   = bid >> 2;
    const int cg  = bid & 3;
    const int C0  = cg * 64;
    const int kk  = t >> 6;                  // 0..7
    const int c   = t & 63;

    // ---- issue the whole W2 slice first: 512 thr x 32 x 4B = 64 KB ----
    float w2[32];
    #pragma unroll
    for (int j = 0; j < 32; ++j)
        w2[j] = W2[(kk * 32 + j) * D_SZ + C0 + c];

    if (t < VOCAB) s_cnt[t] = ws[CNT_OFF + b * VOCAB + t];
    __syncthreads();

    // ---- layer 1 via EW1: 33-FMA dot per hidden feature ----
    if (t < D_SZ) {
        float a = b1[t];
        #pragma unroll
        for (int v = 0; v < VOCAB; ++v)
            a = fmaf(s_cnt[v], ws[EW1_OFF + v * D_SZ + t], a);
        s_h[t] = fmaxf(a, 0.f);
    }
    __syncthreads();

    // ---- layer 2 slice from registers ----
    float acc = 0.f;
    #pragma unroll
    for (int j = 0; j < 32; ++j)
        acc = fmaf(s_h[kk * 32 + j], w2[j], acc);
    s_p[kk][c] = acc;
    __syncthreads();

    if (t < 64) {
        float o = b2[C0 + t];
        #pragma unroll
        for (int q = 0; q < 8; ++q) o += s_p[q][t];
        out[(size_t)b * D_SZ + C0 + t] = fmaxf(o, 0.f);
    }
}

extern "C" void kernel_launch(void* const* d_in, const int* in_sizes, int n_in,
                              void* d_out, int out_size, void* d_ws, size_t ws_size,
                              hipStream_t stream) {
    const int*   X          = (const int*)d_in[0];
    const int*   valid_lens = (const int*)d_in[1];
    const float* emb        = (const float*)d_in[2];
    const float* W1         = (const float*)d_in[3];
    const float* b1         = (const float*)d_in[4];
    const float* W2         = (const float*)d_in[5];
    const float* b2         = (const float*)d_in[6];
    float* out = (float*)d_out;
    float* ws  = (float*)d_ws;

    prot_prep<<<80, 512, 0, stream>>>(X, valid_lens, emb, W1, ws);
    prot_main<<<256, 512, 0, stream>>>(ws, b1, W2, b2, out);
}